// Round 7
// baseline (502.756 us; speedup 1.0000x reference)
//
#include <hip/hip_runtime.h>
#include <hip/hip_bf16.h>
#include <math.h>

#define N_NODES 20000
#define N_EDGES 640000
#define ET_EDGES (N_EDGES + N_NODES)   // with self-loops
#define G_GRAPHS 64
#define NEG_SLOPE 0.2f

typedef __attribute__((ext_vector_type(8))) short s8v;   // 8 bf16 (4 VGPR)
typedef __attribute__((ext_vector_type(4))) float f4v;   // 4 fp32 acc

// fp32 -> bf16 (RNE) and back
__device__ __forceinline__ unsigned short bf_hi(float f) {
    union { float f; unsigned int u; } c; c.f = f;
    unsigned int r = (c.u + 0x7fffu + ((c.u >> 16) & 1u)) >> 16;
    return (unsigned short)r;
}
__device__ __forceinline__ float bf_f(unsigned short h) {
    union { unsigned int u; float f; } c; c.u = ((unsigned int)h) << 16;
    return c.f;
}

// ---------------- CSR construction (+ graph bounds folded in) ----------------

__global__ void hist_dst(const int* __restrict__ ei, int* __restrict__ cnt,
                         const int* __restrict__ batch, int* __restrict__ gstart) {
    int j = blockIdx.x * blockDim.x + threadIdx.x;
    if (blockIdx.x == 0 && threadIdx.x <= G_GRAPHS) {
        int g = threadIdx.x;
        int lo = 0, hi = N_NODES;
        while (lo < hi) {              // first i with batch[i] >= g
            int mid = (lo + hi) >> 1;
            if (batch[mid] < g) lo = mid + 1; else hi = mid;
        }
        gstart[g] = lo;
    }
    if (j >= ET_EDGES) return;
    int d = (j < N_EDGES) ? ei[N_EDGES + j] : (j - N_EDGES);
    atomicAdd(&cnt[d], 1);
}

__global__ __launch_bounds__(1024) void scan_rowptr(const int* __restrict__ cnt,
                                                    int* __restrict__ row_ptr) {
    __shared__ int sums[1024];
    const int n = N_NODES;
    const int CH = (n + 1023) / 1024;   // 20
    int t = threadIdx.x;
    int base = t * CH;
    int s = 0;
    for (int i = 0; i < CH; ++i) {
        int idx = base + i;
        if (idx < n) s += cnt[idx];
    }
    sums[t] = s;
    __syncthreads();
    for (int o = 1; o < 1024; o <<= 1) {
        int v = (t >= o) ? sums[t - o] : 0;
        __syncthreads();
        sums[t] += v;
        __syncthreads();
    }
    int run = (t == 0) ? 0 : sums[t - 1];
    for (int i = 0; i < CH; ++i) {
        int idx = base + i;
        if (idx < n) { row_ptr[idx] = run; run += cnt[idx]; }
    }
    if (t == 1023) row_ptr[n] = sums[1023];
}

__global__ void fill_csr(const int* __restrict__ ei, const int* __restrict__ row_ptr,
                         int* __restrict__ cur, int* __restrict__ col) {
    int j = blockIdx.x * blockDim.x + threadIdx.x;
    if (j >= ET_EDGES) return;
    int s, d;
    if (j < N_EDGES) { s = ei[j]; d = ei[N_EDGES + j]; }
    else             { s = d = j - N_EDGES; }
    int pos = row_ptr[d] + atomicAdd(&cur[d], 1);
    col[pos] = s;
}

// ---------------- fused prep: x/W splits + buffer zeroing -------------------

__global__ void prep_split(const float* __restrict__ x,
                           const float* __restrict__ W1, const float* __restrict__ W2,
                           const float* __restrict__ W3,
                           unsigned short* __restrict__ xh, unsigned short* __restrict__ xl,
                           unsigned short* __restrict__ w1h, unsigned short* __restrict__ w1l,
                           unsigned short* __restrict__ w2h, unsigned short* __restrict__ w2l,
                           unsigned short* __restrict__ w3h, unsigned short* __restrict__ w3l,
                           int* __restrict__ cntcur, float* __restrict__ gout) {
    int idx = blockIdx.x * blockDim.x + threadIdx.x;
    if (idx < 640000) {                     // x: [20000*128] f32 -> hi/lo, vec4
        int i = idx * 4;
        float4 v = *(const float4*)&x[i];
        ushort4 h, l;
        h.x = bf_hi(v.x); l.x = bf_hi(v.x - bf_f(h.x));
        h.y = bf_hi(v.y); l.y = bf_hi(v.y - bf_f(h.y));
        h.z = bf_hi(v.z); l.z = bf_hi(v.z - bf_f(h.z));
        h.w = bf_hi(v.w); l.w = bf_hi(v.w - bf_f(h.w));
        *(ushort4*)&xh[i] = h;
        *(ushort4*)&xl[i] = l;
        return;
    }
    idx -= 640000;
    if (idx < 32768) {                      // W1 [128][256] -> [256][128]
        int k = idx / 256, n = idx % 256;
        float v = W1[idx];
        unsigned short h = bf_hi(v);
        w1h[n * 128 + k] = h;
        w1l[n * 128 + k] = bf_hi(v - bf_f(h));
        return;
    }
    idx -= 32768;
    if (idx < 65536) {                      // W2 [256][256] -> [256][256]
        int k = idx / 256, n = idx % 256;
        float v = W2[idx];
        unsigned short h = bf_hi(v);
        w2h[n * 256 + k] = h;
        w2l[n * 256 + k] = bf_hi(v - bf_f(h));
        return;
    }
    idx -= 65536;
    if (idx < 32768) {                      // W3 [256][128] -> [128][256]
        int k = idx / 128, n = idx % 128;
        float v = W3[idx];
        unsigned short h = bf_hi(v);
        w3h[n * 256 + k] = h;
        w3l[n * 256 + k] = bf_hi(v - bf_f(h));
        return;
    }
    idx -= 32768;
    if (idx < 10000) {                      // zero cnt+cur (40000 ints, vec4)
        *(int4*)&cntcur[idx * 4] = make_int4(0, 0, 0, 0);
        return;
    }
    idx -= 10000;
    if (idx < 2048) {                       // zero gout (8192 floats, vec4)
        *(float4*)&gout[idx * 4] = make_float4(0.f, 0.f, 0.f, 0.f);
    }
}

// ---------------- split-bf16 MFMA GEMM: C = A @ B, fp32-accurate ------------
// C = Ah*Bh + Ah*Bl + Al*Bh (lo*lo ~2^-18 rel, dropped). fp32 accumulate.

#define LDT 40

__global__ __launch_bounds__(256) void gemm_split(
        const unsigned short* __restrict__ Ah, const unsigned short* __restrict__ Al,
        const unsigned short* __restrict__ Bh, const unsigned short* __restrict__ Bl,
        float* __restrict__ C, int M, int Nc, int K) {
    __shared__ unsigned short lAh[128 * LDT];
    __shared__ unsigned short lAl[128 * LDT];
    __shared__ unsigned short lBh[64 * LDT];
    __shared__ unsigned short lBl[64 * LDT];
    int bm = blockIdx.x * 128, bn = blockIdx.y * 64;
    int t = threadIdx.x, w = t >> 6, lane = t & 63;
    int wm = (w >> 1) * 64, wn = (w & 1) * 32;

    f4v acc[4][2] = {};

    int sr = t >> 1, sk = (t & 1) << 4;     // A: row, k-offset {0,16}
    int br = t >> 2, bk = (t & 3) << 3;     // B: row, k-offset {0,8,16,24}
    int ar = bm + sr; if (ar >= M) ar = M - 1;
    const unsigned short* pAh = Ah + (size_t)ar * K + sk;
    const unsigned short* pAl = Al + (size_t)ar * K + sk;
    const unsigned short* pBh = Bh + (size_t)(bn + br) * K + bk;
    const unsigned short* pBl = Bl + (size_t)(bn + br) * K + bk;

    int fr = lane & 15, fk = (lane >> 4) << 3;

    for (int k0 = 0; k0 < K; k0 += 32) {
        uint4 vh0 = *(const uint4*)(pAh + k0);
        uint4 vh1 = *(const uint4*)(pAh + k0 + 8);
        uint4 vl0 = *(const uint4*)(pAl + k0);
        uint4 vl1 = *(const uint4*)(pAl + k0 + 8);
        uint4 wh  = *(const uint4*)(pBh + k0);
        uint4 wl  = *(const uint4*)(pBl + k0);
        __syncthreads();
        *(uint4*)&lAh[sr * LDT + sk]     = vh0;
        *(uint4*)&lAh[sr * LDT + sk + 8] = vh1;
        *(uint4*)&lAl[sr * LDT + sk]     = vl0;
        *(uint4*)&lAl[sr * LDT + sk + 8] = vl1;
        *(uint4*)&lBh[br * LDT + bk] = wh;
        *(uint4*)&lBl[br * LDT + bk] = wl;
        __syncthreads();

        s8v a_h[4], a_l[4], b_h[2], b_l[2];
        #pragma unroll
        for (int mi = 0; mi < 4; ++mi) {
            a_h[mi] = *(const s8v*)&lAh[(wm + mi * 16 + fr) * LDT + fk];
            a_l[mi] = *(const s8v*)&lAl[(wm + mi * 16 + fr) * LDT + fk];
        }
        #pragma unroll
        for (int nj = 0; nj < 2; ++nj) {
            b_h[nj] = *(const s8v*)&lBh[(wn + nj * 16 + fr) * LDT + fk];
            b_l[nj] = *(const s8v*)&lBl[(wn + nj * 16 + fr) * LDT + fk];
        }
        #pragma unroll
        for (int mi = 0; mi < 4; ++mi)
            #pragma unroll
            for (int nj = 0; nj < 2; ++nj) {
                acc[mi][nj] = __builtin_amdgcn_mfma_f32_16x16x32_bf16(
                    a_h[mi], b_h[nj], acc[mi][nj], 0, 0, 0);
                acc[mi][nj] = __builtin_amdgcn_mfma_f32_16x16x32_bf16(
                    a_h[mi], b_l[nj], acc[mi][nj], 0, 0, 0);
                acc[mi][nj] = __builtin_amdgcn_mfma_f32_16x16x32_bf16(
                    a_l[mi], b_h[nj], acc[mi][nj], 0, 0, 0);
            }
    }

    // C/D layout: col = lane&15, row = (lane>>4)*4 + q  [verified gfx950]
    #pragma unroll
    for (int mi = 0; mi < 4; ++mi)
        #pragma unroll
        for (int nj = 0; nj < 2; ++nj) {
            int row0 = bm + wm + mi * 16 + (lane >> 4) * 4;
            int colc = bn + wn + nj * 16 + (lane & 15);
            #pragma unroll
            for (int q = 0; q < 4; ++q) {
                int r = row0 + q;
                if (r < M) C[(size_t)r * Nc + colc] = acc[mi][nj][q];
            }
        }
}

// ---------------- per-node attention coefficients (interleaved [N][H]) ------

template <int HEADS, int C>
__global__ __launch_bounds__(256) void node_alpha3(const float* __restrict__ h,
                                                   const float* __restrict__ a_src,
                                                   const float* __restrict__ a_dst,
                                                   float* __restrict__ asi,   // [N][H]
                                                   float* __restrict__ adi) { // [N][H]
    constexpr int F = HEADS * C;
    constexpr int VEC = F / 64;        // 4 (F=256) or 2 (F=128)
    constexpr int LPH = C / VEC;       // lanes per head: 16 or 64
    int wid = threadIdx.x >> 6, lane = threadIdx.x & 63;
    int v = blockIdx.x * 4 + wid;
    if (v >= N_NODES) return;
    const float* hp = h + (size_t)v * F + lane * VEC;
    float ps = 0.f, pd = 0.f;
    #pragma unroll
    for (int c = 0; c < VEC; ++c) {
        float hv = hp[c];
        ps = fmaf(hv, a_src[lane * VEC + c], ps);
        pd = fmaf(hv, a_dst[lane * VEC + c], pd);
    }
    #pragma unroll
    for (int o = LPH / 2; o; o >>= 1) {
        ps += __shfl_xor(ps, o);
        pd += __shfl_xor(pd, o);
    }
    if ((lane & (LPH - 1)) == 0) {
        int head = lane / LPH;
        asi[v * HEADS + head] = ps;
        adi[v * HEADS + head] = pd;
    }
}

// ---------------- per-edge attention weights (unnormalized, head-major) -----

template <int H>
__global__ __launch_bounds__(256) void edge_alpha2(
        const float* __restrict__ asi,    // [N][H]
        const float* __restrict__ adi,    // [N][H]
        const int* __restrict__ row_ptr,
        const int* __restrict__ col,
        float* __restrict__ pex,          // [H][ET]
        float* __restrict__ dn) {         // [N][H]
    int wid = threadIdx.x >> 6, lane = threadIdx.x & 63;
    int v = blockIdx.x * 4 + wid;
    if (v >= N_NODES) return;
    int r0 = row_ptr[v], r1 = row_ptr[v + 1];
    float adh[H];
    #pragma unroll
    for (int t = 0; t < H; ++t) adh[t] = adi[v * H + t];
    float ls[H] = {};
    for (int base = r0; base < r1; base += 64) {
        int j = base + lane;
        bool valid = j < r1;
        int s = col[valid ? j : r0];
        if (H == 4) {
            float4 a4 = *(const float4*)&asi[(size_t)s * 4];
            float as_[4] = { a4.x, a4.y, a4.z, a4.w };
            #pragma unroll
            for (int t = 0; t < 4; ++t) {
                float e = as_[t] + adh[t];
                e = (e > 0.f) ? e : NEG_SLOPE * e;
                float p = valid ? __expf(e) : 0.f;
                ls[t] += p;
                if (valid) pex[(size_t)t * ET_EDGES + j] = p;
            }
        } else {
            float e = asi[s] + adh[0];
            e = (e > 0.f) ? e : NEG_SLOPE * e;
            float p = valid ? __expf(e) : 0.f;
            ls[0] += p;
            if (valid) pex[j] = p;
        }
    }
    #pragma unroll
    for (int t = 0; t < H; ++t)
        #pragma unroll
        for (int o = 32; o; o >>= 1) ls[t] += __shfl_xor(ls[t], o);
    if (lane == 0) {
        #pragma unroll
        for (int t = 0; t < H; ++t) dn[v * H + t] = ls[t];
    }
}

// ---------------- channel-sliced weighted-gather aggregate ------------------
// NSLICE=8 (R7): slice = blockIdx & 7 -> with %8 XCD round-robin, slice s
// pins to XCD s; per-XCD h working set = N*SCH*4B = 2.5 MB (L1/2) / 1.25 MB
// (L3) -> FITS the 4 MB per-XCD L2 (R4 evidence: FETCH 112->21 MB). The
// per-slice edge phase is only 2 coalesced loads + 2 ds_writes (pex is
// precomputed by edge_alpha2) -- the component that made R4's NSLICE=8 lose
// is gone. Tail uses exact group granularity (GATHER4/2/1, no pad waste).

template <int NSLICE, int SCH, int F, int H, bool DO_ELU, bool SPLIT>
__global__ __launch_bounds__(256) void gat_aggregate4(
        const float* __restrict__ h,      // [N][F]
        const float* __restrict__ pex,    // [H][ET] unnormalized
        const float* __restrict__ dn,     // [N][H]
        const int* __restrict__ row_ptr,
        const int* __restrict__ col,
        const float* __restrict__ bias,   // [F]
        float* __restrict__ out,          // [N][F]  (SPLIT=false)
        unsigned short* __restrict__ oh,  // [N][F]  (SPLIT=true)
        unsigned short* __restrict__ ol) {
    constexpr int CL = SCH / 4;           // lanes per edge (8 or 4)
    constexpr int E  = 64 / CL;           // parallel edges (8 or 16)
    constexpr int CPH = F / H;            // channels per head
    __shared__ int   s_off[4][64];
    __shared__ float s_p[4][64];
    int slice = blockIdx.x & (NSLICE - 1);
    int ng = blockIdx.x / NSLICE;
    int wid = threadIdx.x >> 6, lane = threadIdx.x & 63;
    int v = ng * 4 + wid;
    if (v >= N_NODES) return;
    int head = (slice * SCH) / CPH;
    int eg = lane / CL, cl = lane % CL;
    int r0 = row_ptr[v], r1 = row_ptr[v + 1];
    const float* pp = pex + (size_t)head * ET_EDGES;
    float acc[4] = {};
    const char* hb = (const char*)(h + slice * SCH + cl * 4);

#define GATHERN(gg, NN)                                                    \
    {                                                                      \
        int kk[NN]; float pw[NN]; int ow[NN];                              \
        _Pragma("unroll")                                                  \
        for (int u = 0; u < NN; ++u) kk[u] = ((gg) + u) * E + eg;          \
        _Pragma("unroll")                                                  \
        for (int u = 0; u < NN; ++u) { pw[u] = s_p[wid][kk[u]];            \
                                       ow[u] = s_off[wid][kk[u]]; }        \
        float4 hw[NN];                                                     \
        _Pragma("unroll")                                                  \
        for (int u = 0; u < NN; ++u) hw[u] = *(const float4*)(hb + ow[u]); \
        _Pragma("unroll")                                                  \
        for (int u = 0; u < NN; ++u) {                                     \
            acc[0] = fmaf(pw[u], hw[u].x, acc[0]);                         \
            acc[1] = fmaf(pw[u], hw[u].y, acc[1]);                         \
            acc[2] = fmaf(pw[u], hw[u].z, acc[2]);                         \
            acc[3] = fmaf(pw[u], hw[u].w, acc[3]);                         \
        }                                                                  \
    }

    for (int base = r0; base < r1; base += 64) {
        int j = base + lane;
        bool valid = j < r1;
        int s = col[valid ? j : r0];
        float p = valid ? pp[j] : 0.f;     // coalesced precomputed weight
        s_p[wid][lane] = p;
        s_off[wid][lane] = s * (F * 4);    // byte offset of row s

        int nk = min(64, r1 - base);
        int nkg = (nk + E - 1) / E;        // <= 64/E groups this window
        int g = 0;
        for (; g + 4 <= nkg; g += 4) GATHERN(g, 4);
        if (g + 2 <= nkg) { GATHERN(g, 2); g += 2; }
        if (g < nkg) GATHERN(g, 1);
    }
#undef GATHERN

    // reduce acc across edge groups (lanes differing in bits >= log2(CL))
    #pragma unroll
    for (int c = 0; c < 4; ++c) {
        #pragma unroll
        for (int o = CL; o < 64; o <<= 1) acc[c] += __shfl_xor(acc[c], o);
    }
    if (eg == 0) {
        float inv = 1.f / (dn[v * H + head] + 1e-16f);
        int ch0 = slice * SCH + cl * 4;
        float o4[4];
        #pragma unroll
        for (int c = 0; c < 4; ++c) {
            float o = acc[c] * inv + bias[ch0 + c];
            if (DO_ELU) o = (o > 0.f) ? o : expm1f(o);
            o4[c] = o;
        }
        if constexpr (SPLIT) {
            ushort4 hv4, lv4;
            hv4.x = bf_hi(o4[0]); lv4.x = bf_hi(o4[0] - bf_f(hv4.x));
            hv4.y = bf_hi(o4[1]); lv4.y = bf_hi(o4[1] - bf_f(hv4.y));
            hv4.z = bf_hi(o4[2]); lv4.z = bf_hi(o4[2] - bf_f(hv4.z));
            hv4.w = bf_hi(o4[3]); lv4.w = bf_hi(o4[3] - bf_f(hv4.w));
            *(ushort4*)&oh[(size_t)v * F + ch0] = hv4;
            *(ushort4*)&ol[(size_t)v * F + ch0] = lv4;
        } else {
            *(float4*)&out[(size_t)v * F + ch0] =
                make_float4(o4[0], o4[1], o4[2], o4[3]);
        }
    }
}

// ---------------- global mean pool: 4-way row-split + atomic combine --------

__global__ void pool_mean4(const float* __restrict__ hout, const int* __restrict__ gstart,
                           float* __restrict__ gout) {
    int g = blockIdx.x;       // 64
    int q = blockIdx.y;       // 4 row-quarters
    int c = threadIdx.x;      // 128 channels
    int off = gstart[g], end = gstart[g + 1];
    float inv = 1.f / fmaxf((float)(end - off), 1.0f);
    float s = 0.f;
    for (int i = off + q; i < end; i += 4) s += hout[(size_t)i * 128 + c];
    atomicAdd(&gout[g * 128 + c], s * inv);
}

// ---------------- launch ----------------

static inline size_t align_up(size_t x, size_t a) { return (x + a - 1) & ~(a - 1); }

extern "C" void kernel_launch(void* const* d_in, const int* in_sizes, int n_in,
                              void* d_out, int out_size, void* d_ws, size_t ws_size,
                              hipStream_t stream) {
    const float* x   = (const float*)d_in[0];
    const int*   ei  = (const int*)d_in[1];
    const int*   bat = (const int*)d_in[2];
    const float* W1  = (const float*)d_in[3];
    const float* as1 = (const float*)d_in[4];
    const float* ad1 = (const float*)d_in[5];
    const float* b1  = (const float*)d_in[6];
    const float* W2  = (const float*)d_in[7];
    const float* as2 = (const float*)d_in[8];
    const float* ad2 = (const float*)d_in[9];
    const float* b2  = (const float*)d_in[10];
    const float* W3  = (const float*)d_in[11];
    const float* as3 = (const float*)d_in[12];
    const float* ad3 = (const float*)d_in[13];
    const float* b3  = (const float*)d_in[14];

    float* gout = (float*)d_out;                     // [G,128]
    float* hout = (float*)d_out + G_GRAPHS * 128;    // [N,128]

    char* w = (char*)d_ws;
    size_t o = 0;
    float* bufA = (float*)(w + o);           o = align_up(o + (size_t)N_NODES * 256 * 4, 256);
    unsigned short* Bh = (unsigned short*)(w + o); o = align_up(o + (size_t)N_NODES * 256 * 2, 256);
    unsigned short* Bl = (unsigned short*)(w + o); o = align_up(o + (size_t)N_NODES * 256 * 2, 256);
    unsigned short* xh = (unsigned short*)(w + o); o = align_up(o + (size_t)N_NODES * 128 * 2, 256);
    unsigned short* xl = (unsigned short*)(w + o); o = align_up(o + (size_t)N_NODES * 128 * 2, 256);
    unsigned short* Wt1h = (unsigned short*)(w + o); o = align_up(o + (size_t)256 * 128 * 2, 256);
    unsigned short* Wt1l = (unsigned short*)(w + o); o = align_up(o + (size_t)256 * 128 * 2, 256);
    unsigned short* Wt2h = (unsigned short*)(w + o); o = align_up(o + (size_t)256 * 256 * 2, 256);
    unsigned short* Wt2l = (unsigned short*)(w + o); o = align_up(o + (size_t)256 * 256 * 2, 256);
    unsigned short* Wt3h = (unsigned short*)(w + o); o = align_up(o + (size_t)128 * 256 * 2, 256);
    unsigned short* Wt3l = (unsigned short*)(w + o); o = align_up(o + (size_t)128 * 256 * 2, 256);
    float* asv  = (float*)(w + o); o = align_up(o + (size_t)N_NODES * 4 * 4, 256);
    float* adv  = (float*)(w + o); o = align_up(o + (size_t)N_NODES * 4 * 4, 256);
    float* pex  = (float*)(w + o); o = align_up(o + (size_t)ET_EDGES * 4 * 4, 256);
    float* dnv  = (float*)(w + o); o = align_up(o + (size_t)N_NODES * 4 * 4, 256);
    int* row_ptr = (int*)(w + o);  o = align_up(o + (size_t)(N_NODES + 1) * 4, 256);
    int* col     = (int*)(w + o);  o = align_up(o + (size_t)ET_EDGES * 4, 256);
    int* cnt     = (int*)(w + o);  o += (size_t)N_NODES * 4;        // cnt+cur contiguous
    int* cur     = (int*)(w + o);  o = align_up(o + (size_t)N_NODES * 4, 256);
    int* gstart  = (int*)(w + o);  o = align_up(o + (size_t)(G_GRAPHS + 1) * 4, 256);

    // ---- fused prep (splits + zeroing) + CSR build ----
    {
        int total = 640000 + 32768 + 65536 + 32768 + 10000 + 2048;
        prep_split<<<(total + 255) / 256, 256, 0, stream>>>(
            x, W1, W2, W3, xh, xl, Wt1h, Wt1l, Wt2h, Wt2l, Wt3h, Wt3l, cnt, gout);
    }
    hist_dst<<<(ET_EDGES + 255) / 256, 256, 0, stream>>>(ei, cnt, bat, gstart);
    scan_rowptr<<<1, 1024, 0, stream>>>(cnt, row_ptr);
    fill_csr<<<(ET_EDGES + 255) / 256, 256, 0, stream>>>(ei, row_ptr, cur, col);

    int gm = (N_NODES + 127) / 128;   // 157
    int nb = (N_NODES + 3) / 4;       // 4 nodes (waves) per block: 5000 blocks
    int nbs = nb * 8;                 // x8 channel slices

    // ---- layer 1: 128 -> 4x64 ----
    gemm_split<<<dim3(gm, 4), 256, 0, stream>>>(xh, xl, Wt1h, Wt1l, bufA, N_NODES, 256, 128);
    node_alpha3<4, 64><<<nb, 256, 0, stream>>>(bufA, as1, ad1, asv, adv);
    edge_alpha2<4><<<nb, 256, 0, stream>>>(asv, adv, row_ptr, col, pex, dnv);
    gat_aggregate4<8, 32, 256, 4, true, true><<<nbs, 256, 0, stream>>>(
        bufA, pex, dnv, row_ptr, col, b1, nullptr, Bh, Bl);

    // ---- layer 2: 256 -> 4x64 ----
    gemm_split<<<dim3(gm, 4), 256, 0, stream>>>(Bh, Bl, Wt2h, Wt2l, bufA, N_NODES, 256, 256);
    node_alpha3<4, 64><<<nb, 256, 0, stream>>>(bufA, as2, ad2, asv, adv);
    edge_alpha2<4><<<nb, 256, 0, stream>>>(asv, adv, row_ptr, col, pex, dnv);
    gat_aggregate4<8, 32, 256, 4, true, true><<<nbs, 256, 0, stream>>>(
        bufA, pex, dnv, row_ptr, col, b2, nullptr, Bh, Bl);

    // ---- layer 3: 256 -> 128 (1 head, no concat, no elu) ----
    gemm_split<<<dim3(gm, 2), 256, 0, stream>>>(Bh, Bl, Wt3h, Wt3l, bufA, N_NODES, 128, 256);
    node_alpha3<1, 128><<<nb, 256, 0, stream>>>(bufA, as3, ad3, asv, adv);
    edge_alpha2<1><<<nb, 256, 0, stream>>>(asv, adv, row_ptr, col, pex, dnv);
    gat_aggregate4<8, 16, 128, 1, false, false><<<nbs, 256, 0, stream>>>(
        bufA, pex, dnv, row_ptr, col, b3, hout, nullptr, nullptr);

    // ---- global mean pool ----
    pool_mean4<<<dim3(G_GRAPHS, 4), 128, 0, stream>>>(hout, gstart, gout);
}

// Round 8
// 441.648 us; speedup vs baseline: 1.1384x; 1.1384x over previous
//
#include <hip/hip_runtime.h>
#include <hip/hip_bf16.h>
#include <math.h>

#define N_NODES 20000
#define N_EDGES 640000
#define ET_EDGES (N_EDGES + N_NODES)   // with self-loops
#define G_GRAPHS 64
#define NEG_SLOPE 0.2f

typedef __attribute__((ext_vector_type(8))) short s8v;   // 8 bf16 (4 VGPR)
typedef __attribute__((ext_vector_type(4))) float f4v;   // 4 fp32 acc

// fp32 -> bf16 (RNE) and back
__device__ __forceinline__ unsigned short bf_hi(float f) {
    union { float f; unsigned int u; } c; c.f = f;
    unsigned int r = (c.u + 0x7fffu + ((c.u >> 16) & 1u)) >> 16;
    return (unsigned short)r;
}
__device__ __forceinline__ float bf_f(unsigned short h) {
    union { unsigned int u; float f; } c; c.u = ((unsigned int)h) << 16;
    return c.f;
}

// ---------------- CSR construction (+ graph bounds folded in) ----------------

__global__ void hist_dst(const int* __restrict__ ei, int* __restrict__ cnt,
                         const int* __restrict__ batch, int* __restrict__ gstart) {
    int j = blockIdx.x * blockDim.x + threadIdx.x;
    if (blockIdx.x == 0 && threadIdx.x <= G_GRAPHS) {
        int g = threadIdx.x;
        int lo = 0, hi = N_NODES;
        while (lo < hi) {              // first i with batch[i] >= g
            int mid = (lo + hi) >> 1;
            if (batch[mid] < g) lo = mid + 1; else hi = mid;
        }
        gstart[g] = lo;
    }
    if (j >= ET_EDGES) return;
    int d = (j < N_EDGES) ? ei[N_EDGES + j] : (j - N_EDGES);
    atomicAdd(&cnt[d], 1);
}

__global__ __launch_bounds__(1024) void scan_rowptr(const int* __restrict__ cnt,
                                                    int* __restrict__ row_ptr) {
    __shared__ int sums[1024];
    const int n = N_NODES;
    const int CH = (n + 1023) / 1024;   // 20
    int t = threadIdx.x;
    int base = t * CH;
    int s = 0;
    for (int i = 0; i < CH; ++i) {
        int idx = base + i;
        if (idx < n) s += cnt[idx];
    }
    sums[t] = s;
    __syncthreads();
    for (int o = 1; o < 1024; o <<= 1) {
        int v = (t >= o) ? sums[t - o] : 0;
        __syncthreads();
        sums[t] += v;
        __syncthreads();
    }
    int run = (t == 0) ? 0 : sums[t - 1];
    for (int i = 0; i < CH; ++i) {
        int idx = base + i;
        if (idx < n) { row_ptr[idx] = run; run += cnt[idx]; }
    }
    if (t == 1023) row_ptr[n] = sums[1023];
}

__global__ void fill_csr(const int* __restrict__ ei, const int* __restrict__ row_ptr,
                         int* __restrict__ cur, int* __restrict__ col) {
    int j = blockIdx.x * blockDim.x + threadIdx.x;
    if (j >= ET_EDGES) return;
    int s, d;
    if (j < N_EDGES) { s = ei[j]; d = ei[N_EDGES + j]; }
    else             { s = d = j - N_EDGES; }
    int pos = row_ptr[d] + atomicAdd(&cur[d], 1);
    col[pos] = s;
}

// ---------------- fused prep: x/W splits + buffer zeroing -------------------

__global__ void prep_split(const float* __restrict__ x,
                           const float* __restrict__ W1, const float* __restrict__ W2,
                           const float* __restrict__ W3,
                           unsigned short* __restrict__ xh, unsigned short* __restrict__ xl,
                           unsigned short* __restrict__ w1h, unsigned short* __restrict__ w1l,
                           unsigned short* __restrict__ w2h, unsigned short* __restrict__ w2l,
                           unsigned short* __restrict__ w3h, unsigned short* __restrict__ w3l,
                           int* __restrict__ cntcur, float* __restrict__ gout) {
    int idx = blockIdx.x * blockDim.x + threadIdx.x;
    if (idx < 640000) {                     // x: [20000*128] f32 -> hi/lo, vec4
        int i = idx * 4;
        float4 v = *(const float4*)&x[i];
        ushort4 h, l;
        h.x = bf_hi(v.x); l.x = bf_hi(v.x - bf_f(h.x));
        h.y = bf_hi(v.y); l.y = bf_hi(v.y - bf_f(h.y));
        h.z = bf_hi(v.z); l.z = bf_hi(v.z - bf_f(h.z));
        h.w = bf_hi(v.w); l.w = bf_hi(v.w - bf_f(h.w));
        *(ushort4*)&xh[i] = h;
        *(ushort4*)&xl[i] = l;
        return;
    }
    idx -= 640000;
    if (idx < 32768) {                      // W1 [128][256] -> [256][128]
        int k = idx / 256, n = idx % 256;
        float v = W1[idx];
        unsigned short h = bf_hi(v);
        w1h[n * 128 + k] = h;
        w1l[n * 128 + k] = bf_hi(v - bf_f(h));
        return;
    }
    idx -= 32768;
    if (idx < 65536) {                      // W2 [256][256] -> [256][256]
        int k = idx / 256, n = idx % 256;
        float v = W2[idx];
        unsigned short h = bf_hi(v);
        w2h[n * 256 + k] = h;
        w2l[n * 256 + k] = bf_hi(v - bf_f(h));
        return;
    }
    idx -= 65536;
    if (idx < 32768) {                      // W3 [256][128] -> [128][256]
        int k = idx / 128, n = idx % 128;
        float v = W3[idx];
        unsigned short h = bf_hi(v);
        w3h[n * 256 + k] = h;
        w3l[n * 256 + k] = bf_hi(v - bf_f(h));
        return;
    }
    idx -= 32768;
    if (idx < 10000) {                      // zero cnt+cur (40000 ints, vec4)
        *(int4*)&cntcur[idx * 4] = make_int4(0, 0, 0, 0);
        return;
    }
    idx -= 10000;
    if (idx < 2048) {                       // zero gout (8192 floats, vec4)
        *(float4*)&gout[idx * 4] = make_float4(0.f, 0.f, 0.f, 0.f);
    }
}

// ---------------- split-bf16 MFMA GEMM: C = A @ B, fp32-accurate ------------
// C = Ah*Bh + Ah*Bl + Al*Bh (lo*lo ~2^-18 rel, dropped). fp32 accumulate.

#define LDT 40

__global__ __launch_bounds__(256) void gemm_split(
        const unsigned short* __restrict__ Ah, const unsigned short* __restrict__ Al,
        const unsigned short* __restrict__ Bh, const unsigned short* __restrict__ Bl,
        float* __restrict__ C, int M, int Nc, int K) {
    __shared__ unsigned short lAh[128 * LDT];
    __shared__ unsigned short lAl[128 * LDT];
    __shared__ unsigned short lBh[64 * LDT];
    __shared__ unsigned short lBl[64 * LDT];
    int bm = blockIdx.x * 128, bn = blockIdx.y * 64;
    int t = threadIdx.x, w = t >> 6, lane = t & 63;
    int wm = (w >> 1) * 64, wn = (w & 1) * 32;

    f4v acc[4][2] = {};

    int sr = t >> 1, sk = (t & 1) << 4;     // A: row, k-offset {0,16}
    int br = t >> 2, bk = (t & 3) << 3;     // B: row, k-offset {0,8,16,24}
    int ar = bm + sr; if (ar >= M) ar = M - 1;
    const unsigned short* pAh = Ah + (size_t)ar * K + sk;
    const unsigned short* pAl = Al + (size_t)ar * K + sk;
    const unsigned short* pBh = Bh + (size_t)(bn + br) * K + bk;
    const unsigned short* pBl = Bl + (size_t)(bn + br) * K + bk;

    int fr = lane & 15, fk = (lane >> 4) << 3;

    for (int k0 = 0; k0 < K; k0 += 32) {
        uint4 vh0 = *(const uint4*)(pAh + k0);
        uint4 vh1 = *(const uint4*)(pAh + k0 + 8);
        uint4 vl0 = *(const uint4*)(pAl + k0);
        uint4 vl1 = *(const uint4*)(pAl + k0 + 8);
        uint4 wh  = *(const uint4*)(pBh + k0);
        uint4 wl  = *(const uint4*)(pBl + k0);
        __syncthreads();
        *(uint4*)&lAh[sr * LDT + sk]     = vh0;
        *(uint4*)&lAh[sr * LDT + sk + 8] = vh1;
        *(uint4*)&lAl[sr * LDT + sk]     = vl0;
        *(uint4*)&lAl[sr * LDT + sk + 8] = vl1;
        *(uint4*)&lBh[br * LDT + bk] = wh;
        *(uint4*)&lBl[br * LDT + bk] = wl;
        __syncthreads();

        s8v a_h[4], a_l[4], b_h[2], b_l[2];
        #pragma unroll
        for (int mi = 0; mi < 4; ++mi) {
            a_h[mi] = *(const s8v*)&lAh[(wm + mi * 16 + fr) * LDT + fk];
            a_l[mi] = *(const s8v*)&lAl[(wm + mi * 16 + fr) * LDT + fk];
        }
        #pragma unroll
        for (int nj = 0; nj < 2; ++nj) {
            b_h[nj] = *(const s8v*)&lBh[(wn + nj * 16 + fr) * LDT + fk];
            b_l[nj] = *(const s8v*)&lBl[(wn + nj * 16 + fr) * LDT + fk];
        }
        #pragma unroll
        for (int mi = 0; mi < 4; ++mi)
            #pragma unroll
            for (int nj = 0; nj < 2; ++nj) {
                acc[mi][nj] = __builtin_amdgcn_mfma_f32_16x16x32_bf16(
                    a_h[mi], b_h[nj], acc[mi][nj], 0, 0, 0);
                acc[mi][nj] = __builtin_amdgcn_mfma_f32_16x16x32_bf16(
                    a_h[mi], b_l[nj], acc[mi][nj], 0, 0, 0);
                acc[mi][nj] = __builtin_amdgcn_mfma_f32_16x16x32_bf16(
                    a_l[mi], b_h[nj], acc[mi][nj], 0, 0, 0);
            }
    }

    // C/D layout: col = lane&15, row = (lane>>4)*4 + q  [verified gfx950]
    #pragma unroll
    for (int mi = 0; mi < 4; ++mi)
        #pragma unroll
        for (int nj = 0; nj < 2; ++nj) {
            int row0 = bm + wm + mi * 16 + (lane >> 4) * 4;
            int colc = bn + wn + nj * 16 + (lane & 15);
            #pragma unroll
            for (int q = 0; q < 4; ++q) {
                int r = row0 + q;
                if (r < M) C[(size_t)r * Nc + colc] = acc[mi][nj][q];
            }
        }
}

// ---------------- per-node attention coefficients (transposed out) ---------

template <int HEADS, int C>
__global__ __launch_bounds__(256) void node_alpha2(const float* __restrict__ h,
                                                   const float* __restrict__ a_src,
                                                   const float* __restrict__ a_dst,
                                                   float* __restrict__ asT,   // [HEADS][N]
                                                   float* __restrict__ adT) { // [HEADS][N]
    constexpr int F = HEADS * C;
    constexpr int VEC = F / 64;        // 4 (F=256) or 2 (F=128)
    constexpr int LPH = C / VEC;       // lanes per head: 16 or 64
    int wid = threadIdx.x >> 6, lane = threadIdx.x & 63;
    int v = blockIdx.x * 4 + wid;
    if (v >= N_NODES) return;
    const float* hp = h + (size_t)v * F + lane * VEC;
    float ps = 0.f, pd = 0.f;
    #pragma unroll
    for (int c = 0; c < VEC; ++c) {
        float hv = hp[c];
        ps = fmaf(hv, a_src[lane * VEC + c], ps);
        pd = fmaf(hv, a_dst[lane * VEC + c], pd);
    }
    #pragma unroll
    for (int o = LPH / 2; o; o >>= 1) {
        ps += __shfl_xor(ps, o);
        pd += __shfl_xor(pd, o);
    }
    if ((lane & (LPH - 1)) == 0) {
        int head = lane / LPH;
        asT[head * N_NODES + v] = ps;
        adT[head * N_NODES + v] = pd;
    }
}

// ---------------- channel-sliced softmax-aggregate (R3 structure + R8 µopts)
// NSLICE=4 (measured optimum: R5 NSLICE=1 -> 86us HBM-latency-bound; R7
// NSLICE=8 -> 80us issue-bound; NSLICE=4 -> ~62us). Fused softmax edge phase
// (precomputed-pex variant saved only ~1.5us but cost 3 dispatches, R6/R7).
// R8 micro-opts on the dominant gather-VALU term:
//   - int2 LDS slot (off,p): 1 ds_read_b64 per group (was 2 ds_read_b32)
//   - SGPR-base + 32-bit voffset gathers: 1 v_add_u32 (was 64-bit ptr add)
//   - 8-deep gather batches with exact 4/2/1 tail

template <int SCH, int F, int HEADS, bool DO_ELU, bool SPLIT>
__global__ __launch_bounds__(256) void gat_aggregate5(
        const float* __restrict__ h,      // [N][F]
        const float* __restrict__ asT,    // [HEADS][N]
        const float* __restrict__ adT,    // [HEADS][N]
        const int* __restrict__ row_ptr,
        const int* __restrict__ col,
        const float* __restrict__ bias,   // [F]
        float* __restrict__ out,          // [N][F]  (SPLIT=false)
        unsigned short* __restrict__ oh,  // [N][F]  (SPLIT=true)
        unsigned short* __restrict__ ol) {
    constexpr int CL = SCH / 4;           // lanes per edge (16 or 8)
    constexpr int E  = 64 / CL;           // parallel edges (4 or 8)
    constexpr int CPH = F / HEADS;        // channels per head
    __shared__ int2 s_po[4][64];
    int slice = blockIdx.x & 3;           // NSLICE == 4
    int ng = blockIdx.x >> 2;
    int wid = threadIdx.x >> 6, lane = threadIdx.x & 63;
    int v = ng * 4 + wid;
    if (v >= N_NODES) return;
    int head = (slice * SCH) / CPH;       // layers 1/2: slice; layer 3: 0
    int eg = lane / CL, cl = lane % CL;
    int r0 = row_ptr[v], r1 = row_ptr[v + 1];
    float ad = adT[head * N_NODES + v];
    const float* asrc = asT + head * N_NODES;
    float acc[4] = {};
    float lsum = 0.f;
    const char* hbase = (const char*)h;
    unsigned laneByte = (unsigned)((slice * SCH + cl * 4) * 4);

#define GATHERN(gg, NN)                                                      \
    {                                                                        \
        int2 po[NN];                                                         \
        _Pragma("unroll")                                                    \
        for (int u = 0; u < NN; ++u) po[u] = s_po[wid][((gg) + u) * E + eg]; \
        float4 hw[NN];                                                       \
        _Pragma("unroll")                                                    \
        for (int u = 0; u < NN; ++u)                                         \
            hw[u] = *(const float4*)(hbase + (laneByte + (unsigned)po[u].x));\
        _Pragma("unroll")                                                    \
        for (int u = 0; u < NN; ++u) {                                       \
            float pk = __int_as_float(po[u].y);                              \
            acc[0] = fmaf(pk, hw[u].x, acc[0]);                              \
            acc[1] = fmaf(pk, hw[u].y, acc[1]);                              \
            acc[2] = fmaf(pk, hw[u].z, acc[2]);                              \
            acc[3] = fmaf(pk, hw[u].w, acc[3]);                              \
        }                                                                    \
    }

    for (int base = r0; base < r1; base += 64) {
        int j = base + lane;
        bool valid = j < r1;
        int s = col[valid ? j : r0];
        float e = asrc[s] + ad;
        e = (e > 0.f) ? e : NEG_SLOPE * e;
        float p = valid ? __expf(e) : 0.f;
        lsum += p;
        s_po[wid][lane] = make_int2(s * (F * 4), __float_as_int(p));
        // wave-synchronous: wid-private LDS rows, no barrier needed

        int nk = min(64, r1 - base);
        int nkg = (nk + E - 1) / E;        // <= CL groups this window
        int g = 0;
        for (; g + 8 <= nkg; g += 8) GATHERN(g, 8);
        if (g + 4 <= nkg) { GATHERN(g, 4); g += 4; }
        if (g + 2 <= nkg) { GATHERN(g, 2); g += 2; }
        if (g < nkg) GATHERN(g, 1);
    }
#undef GATHERN

    // full-wave softmax denominator
    #pragma unroll
    for (int o = 32; o; o >>= 1) lsum += __shfl_xor(lsum, o);
    // reduce acc across edge groups (lanes differing in bits >= log2(CL))
    #pragma unroll
    for (int c = 0; c < 4; ++c) {
        #pragma unroll
        for (int o = CL; o < 64; o <<= 1) acc[c] += __shfl_xor(acc[c], o);
    }
    if (eg == 0) {
        float inv = 1.f / (lsum + 1e-16f);
        int ch0 = slice * SCH + cl * 4;
        float o4[4];
        #pragma unroll
        for (int c = 0; c < 4; ++c) {
            float o = acc[c] * inv + bias[ch0 + c];
            if (DO_ELU) o = (o > 0.f) ? o : expm1f(o);
            o4[c] = o;
        }
        if constexpr (SPLIT) {
            ushort4 hv4, lv4;
            hv4.x = bf_hi(o4[0]); lv4.x = bf_hi(o4[0] - bf_f(hv4.x));
            hv4.y = bf_hi(o4[1]); lv4.y = bf_hi(o4[1] - bf_f(hv4.y));
            hv4.z = bf_hi(o4[2]); lv4.z = bf_hi(o4[2] - bf_f(hv4.z));
            hv4.w = bf_hi(o4[3]); lv4.w = bf_hi(o4[3] - bf_f(hv4.w));
            *(ushort4*)&oh[(size_t)v * F + ch0] = hv4;
            *(ushort4*)&ol[(size_t)v * F + ch0] = lv4;
        } else {
            *(float4*)&out[(size_t)v * F + ch0] =
                make_float4(o4[0], o4[1], o4[2], o4[3]);
        }
    }
}

// ---------------- global mean pool: 4-way row-split + atomic combine --------

__global__ void pool_mean4(const float* __restrict__ hout, const int* __restrict__ gstart,
                           float* __restrict__ gout) {
    int g = blockIdx.x;       // 64
    int q = blockIdx.y;       // 4 row-quarters
    int c = threadIdx.x;      // 128 channels
    int off = gstart[g], end = gstart[g + 1];
    float inv = 1.f / fmaxf((float)(end - off), 1.0f);
    float s = 0.f;
    for (int i = off + q; i < end; i += 4) s += hout[(size_t)i * 128 + c];
    atomicAdd(&gout[g * 128 + c], s * inv);
}

// ---------------- launch ----------------

static inline size_t align_up(size_t x, size_t a) { return (x + a - 1) & ~(a - 1); }

extern "C" void kernel_launch(void* const* d_in, const int* in_sizes, int n_in,
                              void* d_out, int out_size, void* d_ws, size_t ws_size,
                              hipStream_t stream) {
    const float* x   = (const float*)d_in[0];
    const int*   ei  = (const int*)d_in[1];
    const int*   bat = (const int*)d_in[2];
    const float* W1  = (const float*)d_in[3];
    const float* as1 = (const float*)d_in[4];
    const float* ad1 = (const float*)d_in[5];
    const float* b1  = (const float*)d_in[6];
    const float* W2  = (const float*)d_in[7];
    const float* as2 = (const float*)d_in[8];
    const float* ad2 = (const float*)d_in[9];
    const float* b2  = (const float*)d_in[10];
    const float* W3  = (const float*)d_in[11];
    const float* as3 = (const float*)d_in[12];
    const float* ad3 = (const float*)d_in[13];
    const float* b3  = (const float*)d_in[14];

    float* gout = (float*)d_out;                     // [G,128]
    float* hout = (float*)d_out + G_GRAPHS * 128;    // [N,128]

    char* w = (char*)d_ws;
    size_t o = 0;
    float* bufA = (float*)(w + o);           o = align_up(o + (size_t)N_NODES * 256 * 4, 256);
    unsigned short* Bh = (unsigned short*)(w + o); o = align_up(o + (size_t)N_NODES * 256 * 2, 256);
    unsigned short* Bl = (unsigned short*)(w + o); o = align_up(o + (size_t)N_NODES * 256 * 2, 256);
    unsigned short* xh = (unsigned short*)(w + o); o = align_up(o + (size_t)N_NODES * 128 * 2, 256);
    unsigned short* xl = (unsigned short*)(w + o); o = align_up(o + (size_t)N_NODES * 128 * 2, 256);
    unsigned short* Wt1h = (unsigned short*)(w + o); o = align_up(o + (size_t)256 * 128 * 2, 256);
    unsigned short* Wt1l = (unsigned short*)(w + o); o = align_up(o + (size_t)256 * 128 * 2, 256);
    unsigned short* Wt2h = (unsigned short*)(w + o); o = align_up(o + (size_t)256 * 256 * 2, 256);
    unsigned short* Wt2l = (unsigned short*)(w + o); o = align_up(o + (size_t)256 * 256 * 2, 256);
    unsigned short* Wt3h = (unsigned short*)(w + o); o = align_up(o + (size_t)128 * 256 * 2, 256);
    unsigned short* Wt3l = (unsigned short*)(w + o); o = align_up(o + (size_t)128 * 256 * 2, 256);
    float* asv  = (float*)(w + o); o = align_up(o + (size_t)N_NODES * 4 * 4, 256);
    float* adv  = (float*)(w + o); o = align_up(o + (size_t)N_NODES * 4 * 4, 256);
    int* row_ptr = (int*)(w + o);  o = align_up(o + (size_t)(N_NODES + 1) * 4, 256);
    int* col     = (int*)(w + o);  o = align_up(o + (size_t)ET_EDGES * 4, 256);
    int* cnt     = (int*)(w + o);  o += (size_t)N_NODES * 4;        // cnt+cur contiguous
    int* cur     = (int*)(w + o);  o = align_up(o + (size_t)N_NODES * 4, 256);
    int* gstart  = (int*)(w + o);  o = align_up(o + (size_t)(G_GRAPHS + 1) * 4, 256);

    // ---- fused prep (splits + zeroing) + CSR build ----
    {
        int total = 640000 + 32768 + 65536 + 32768 + 10000 + 2048;
        prep_split<<<(total + 255) / 256, 256, 0, stream>>>(
            x, W1, W2, W3, xh, xl, Wt1h, Wt1l, Wt2h, Wt2l, Wt3h, Wt3l, cnt, gout);
    }
    hist_dst<<<(ET_EDGES + 255) / 256, 256, 0, stream>>>(ei, cnt, bat, gstart);
    scan_rowptr<<<1, 1024, 0, stream>>>(cnt, row_ptr);
    fill_csr<<<(ET_EDGES + 255) / 256, 256, 0, stream>>>(ei, row_ptr, cur, col);

    int gm = (N_NODES + 127) / 128;   // 157
    int nb = (N_NODES + 3) / 4;       // 4 nodes per block
    int nbs = nb * 4;                 // x4 channel slices

    // ---- layer 1: 128 -> 4x64 ----
    gemm_split<<<dim3(gm, 4), 256, 0, stream>>>(xh, xl, Wt1h, Wt1l, bufA, N_NODES, 256, 128);
    node_alpha2<4, 64><<<nb, 256, 0, stream>>>(bufA, as1, ad1, asv, adv);
    gat_aggregate5<64, 256, 4, true, true><<<nbs, 256, 0, stream>>>(
        bufA, asv, adv, row_ptr, col, b1, nullptr, Bh, Bl);

    // ---- layer 2: 256 -> 4x64 ----
    gemm_split<<<dim3(gm, 4), 256, 0, stream>>>(Bh, Bl, Wt2h, Wt2l, bufA, N_NODES, 256, 256);
    node_alpha2<4, 64><<<nb, 256, 0, stream>>>(bufA, as2, ad2, asv, adv);
    gat_aggregate5<64, 256, 4, true, true><<<nbs, 256, 0, stream>>>(
        bufA, asv, adv, row_ptr, col, b2, nullptr, Bh, Bl);

    // ---- layer 3: 256 -> 128 (1 head, no concat, no elu) ----
    gemm_split<<<dim3(gm, 2), 256, 0, stream>>>(Bh, Bl, Wt3h, Wt3l, bufA, N_NODES, 128, 256);
    node_alpha2<1, 128><<<nb, 256, 0, stream>>>(bufA, as3, ad3, asv, adv);
    gat_aggregate5<32, 128, 1, false, false><<<nbs, 256, 0, stream>>>(
        bufA, asv, adv, row_ptr, col, b3, hout, nullptr, nullptr);

    // ---- global mean pool ----
    pool_mean4<<<dim3(G_GRAPHS, 4), 128, 0, stream>>>(hout, gstart, gout);
}

// Round 10
// 425.988 us; speedup vs baseline: 1.1802x; 1.0368x over previous
//
#include <hip/hip_runtime.h>
#include <hip/hip_bf16.h>
#include <math.h>

#define N_NODES 20000
#define N_EDGES 640000
#define ET_EDGES (N_EDGES + N_NODES)   // with self-loops
#define G_GRAPHS 64
#define NEG_SLOPE 0.2f

typedef __attribute__((ext_vector_type(8))) short s8v;   // 8 bf16 (4 VGPR)
typedef __attribute__((ext_vector_type(4))) float f4v;   // 4 fp32 acc

// fp32 -> bf16 (RNE) and back
__device__ __forceinline__ unsigned short bf_hi(float f) {
    union { float f; unsigned int u; } c; c.f = f;
    unsigned int r = (c.u + 0x7fffu + ((c.u >> 16) & 1u)) >> 16;
    return (unsigned short)r;
}
__device__ __forceinline__ float bf_f(unsigned short h) {
    union { unsigned int u; float f; } c; c.u = ((unsigned int)h) << 16;
    return c.f;
}

// ---------------- CSR construction (+ graph bounds folded in) ----------------

__global__ void hist_dst(const int* __restrict__ ei, int* __restrict__ cnt,
                         const int* __restrict__ batch, int* __restrict__ gstart) {
    int j = blockIdx.x * blockDim.x + threadIdx.x;
    if (blockIdx.x == 0 && threadIdx.x <= G_GRAPHS) {
        int g = threadIdx.x;
        int lo = 0, hi = N_NODES;
        while (lo < hi) {              // first i with batch[i] >= g
            int mid = (lo + hi) >> 1;
            if (batch[mid] < g) lo = mid + 1; else hi = mid;
        }
        gstart[g] = lo;
    }
    if (j >= ET_EDGES) return;
    int d = (j < N_EDGES) ? ei[N_EDGES + j] : (j - N_EDGES);
    atomicAdd(&cnt[d], 1);
}

__global__ __launch_bounds__(1024) void scan_rowptr(const int* __restrict__ cnt,
                                                    int* __restrict__ row_ptr) {
    __shared__ int sums[1024];
    const int n = N_NODES;
    const int CH = (n + 1023) / 1024;   // 20
    int t = threadIdx.x;
    int base = t * CH;
    int s = 0;
    for (int i = 0; i < CH; ++i) {
        int idx = base + i;
        if (idx < n) s += cnt[idx];
    }
    sums[t] = s;
    __syncthreads();
    for (int o = 1; o < 1024; o <<= 1) {
        int v = (t >= o) ? sums[t - o] : 0;
        __syncthreads();
        sums[t] += v;
        __syncthreads();
    }
    int run = (t == 0) ? 0 : sums[t - 1];
    for (int i = 0; i < CH; ++i) {
        int idx = base + i;
        if (idx < n) { row_ptr[idx] = run; run += cnt[idx]; }
    }
    if (t == 1023) row_ptr[n] = sums[1023];
}

__global__ void fill_csr(const int* __restrict__ ei, const int* __restrict__ row_ptr,
                         int* __restrict__ cur, int* __restrict__ col) {
    int j = blockIdx.x * blockDim.x + threadIdx.x;
    if (j >= ET_EDGES) return;
    int s, d;
    if (j < N_EDGES) { s = ei[j]; d = ei[N_EDGES + j]; }
    else             { s = d = j - N_EDGES; }
    int pos = row_ptr[d] + atomicAdd(&cur[d], 1);
    col[pos] = s;
}

// ---------------- fused prep: x/W splits + buffer zeroing -------------------
// Zeroes cnt+cur, gout, and ALL per-layer alpha accumulators (360000 f32,
// contiguous) which the GEMM epilogues atomically accumulate into.

__global__ void prep_split(const float* __restrict__ x,
                           const float* __restrict__ W1, const float* __restrict__ W2,
                           const float* __restrict__ W3,
                           unsigned short* __restrict__ xh, unsigned short* __restrict__ xl,
                           unsigned short* __restrict__ w1h, unsigned short* __restrict__ w1l,
                           unsigned short* __restrict__ w2h, unsigned short* __restrict__ w2l,
                           unsigned short* __restrict__ w3h, unsigned short* __restrict__ w3l,
                           int* __restrict__ cntcur, float* __restrict__ gout,
                           float* __restrict__ alphaz) {
    int idx = blockIdx.x * blockDim.x + threadIdx.x;
    if (idx < 640000) {                     // x: [20000*128] f32 -> hi/lo, vec4
        int i = idx * 4;
        float4 v = *(const float4*)&x[i];
        ushort4 h, l;
        h.x = bf_hi(v.x); l.x = bf_hi(v.x - bf_f(h.x));
        h.y = bf_hi(v.y); l.y = bf_hi(v.y - bf_f(h.y));
        h.z = bf_hi(v.z); l.z = bf_hi(v.z - bf_f(h.z));
        h.w = bf_hi(v.w); l.w = bf_hi(v.w - bf_f(h.w));
        *(ushort4*)&xh[i] = h;
        *(ushort4*)&xl[i] = l;
        return;
    }
    idx -= 640000;
    if (idx < 32768) {                      // W1 [128][256] -> [256][128]
        int k = idx / 256, n = idx % 256;
        float v = W1[idx];
        unsigned short h = bf_hi(v);
        w1h[n * 128 + k] = h;
        w1l[n * 128 + k] = bf_hi(v - bf_f(h));
        return;
    }
    idx -= 32768;
    if (idx < 65536) {                      // W2 [256][256] -> [256][256]
        int k = idx / 256, n = idx % 256;
        float v = W2[idx];
        unsigned short h = bf_hi(v);
        w2h[n * 256 + k] = h;
        w2l[n * 256 + k] = bf_hi(v - bf_f(h));
        return;
    }
    idx -= 65536;
    if (idx < 32768) {                      // W3 [256][128] -> [128][256]
        int k = idx / 128, n = idx % 128;
        float v = W3[idx];
        unsigned short h = bf_hi(v);
        w3h[n * 256 + k] = h;
        w3l[n * 256 + k] = bf_hi(v - bf_f(h));
        return;
    }
    idx -= 32768;
    if (idx < 10000) {                      // zero cnt+cur (40000 ints, vec4)
        *(int4*)&cntcur[idx * 4] = make_int4(0, 0, 0, 0);
        return;
    }
    idx -= 10000;
    if (idx < 2048) {                       // zero gout (8192 floats, vec4)
        *(float4*)&gout[idx * 4] = make_float4(0.f, 0.f, 0.f, 0.f);
        return;
    }
    idx -= 2048;
    if (idx < 90000) {                      // zero alpha buffers (360000 f32)
        *(float4*)&alphaz[idx * 4] = make_float4(0.f, 0.f, 0.f, 0.f);
    }
}

// ---------------- split-bf16 MFMA GEMM + fused alpha epilogue ---------------
// C = Ah*Bh + Ah*Bl + Al*Bh (lo*lo ~2^-18 rel, dropped). fp32 accumulate.
// Alpha epilogue (R10 fix): each wave's butterfly covers only its 32-column
// half of the 64-wide col-tile, so BOTH waves atomicAdd their partial dot
// into pre-zeroed asT/adT (R9 direct-store raced the two halves -> 1e-2 err).
// head = bn / CPH: layers 1/2 CPH=64 (block tile == head); layer 3 CPH=128
// (both bn tiles -> head 0, atomics also sum across the two blocks).

#define LDT 40

template <int CPH>
__global__ __launch_bounds__(256) void gemm_split(
        const unsigned short* __restrict__ Ah, const unsigned short* __restrict__ Al,
        const unsigned short* __restrict__ Bh, const unsigned short* __restrict__ Bl,
        float* __restrict__ C, int M, int Nc, int K,
        const float* __restrict__ a_src, const float* __restrict__ a_dst,
        float* __restrict__ asT, float* __restrict__ adT) {
    __shared__ unsigned short lAh[128 * LDT];
    __shared__ unsigned short lAl[128 * LDT];
    __shared__ unsigned short lBh[64 * LDT];
    __shared__ unsigned short lBl[64 * LDT];
    int bm = blockIdx.x * 128, bn = blockIdx.y * 64;
    int t = threadIdx.x, w = t >> 6, lane = t & 63;
    int wm = (w >> 1) * 64, wn = (w & 1) * 32;

    f4v acc[4][2] = {};

    int sr = t >> 1, sk = (t & 1) << 4;     // A: row, k-offset {0,16}
    int br = t >> 2, bk = (t & 3) << 3;     // B: row, k-offset {0,8,16,24}
    int ar = bm + sr; if (ar >= M) ar = M - 1;
    const unsigned short* pAh = Ah + (size_t)ar * K + sk;
    const unsigned short* pAl = Al + (size_t)ar * K + sk;
    const unsigned short* pBh = Bh + (size_t)(bn + br) * K + bk;
    const unsigned short* pBl = Bl + (size_t)(bn + br) * K + bk;

    int fr = lane & 15, fk = (lane >> 4) << 3;

    for (int k0 = 0; k0 < K; k0 += 32) {
        uint4 vh0 = *(const uint4*)(pAh + k0);
        uint4 vh1 = *(const uint4*)(pAh + k0 + 8);
        uint4 vl0 = *(const uint4*)(pAl + k0);
        uint4 vl1 = *(const uint4*)(pAl + k0 + 8);
        uint4 wh  = *(const uint4*)(pBh + k0);
        uint4 wl  = *(const uint4*)(pBl + k0);
        __syncthreads();
        *(uint4*)&lAh[sr * LDT + sk]     = vh0;
        *(uint4*)&lAh[sr * LDT + sk + 8] = vh1;
        *(uint4*)&lAl[sr * LDT + sk]     = vl0;
        *(uint4*)&lAl[sr * LDT + sk + 8] = vl1;
        *(uint4*)&lBh[br * LDT + bk] = wh;
        *(uint4*)&lBl[br * LDT + bk] = wl;
        __syncthreads();

        s8v a_h[4], a_l[4], b_h[2], b_l[2];
        #pragma unroll
        for (int mi = 0; mi < 4; ++mi) {
            a_h[mi] = *(const s8v*)&lAh[(wm + mi * 16 + fr) * LDT + fk];
            a_l[mi] = *(const s8v*)&lAl[(wm + mi * 16 + fr) * LDT + fk];
        }
        #pragma unroll
        for (int nj = 0; nj < 2; ++nj) {
            b_h[nj] = *(const s8v*)&lBh[(wn + nj * 16 + fr) * LDT + fk];
            b_l[nj] = *(const s8v*)&lBl[(wn + nj * 16 + fr) * LDT + fk];
        }
        #pragma unroll
        for (int mi = 0; mi < 4; ++mi)
            #pragma unroll
            for (int nj = 0; nj < 2; ++nj) {
                acc[mi][nj] = __builtin_amdgcn_mfma_f32_16x16x32_bf16(
                    a_h[mi], b_h[nj], acc[mi][nj], 0, 0, 0);
                acc[mi][nj] = __builtin_amdgcn_mfma_f32_16x16x32_bf16(
                    a_h[mi], b_l[nj], acc[mi][nj], 0, 0, 0);
                acc[mi][nj] = __builtin_amdgcn_mfma_f32_16x16x32_bf16(
                    a_l[mi], b_h[nj], acc[mi][nj], 0, 0, 0);
            }
    }

    // C/D layout: col = lane&15, row = (lane>>4)*4 + q  [verified gfx950]
    #pragma unroll
    for (int mi = 0; mi < 4; ++mi)
        #pragma unroll
        for (int nj = 0; nj < 2; ++nj) {
            int row0 = bm + wm + mi * 16 + (lane >> 4) * 4;
            int colc = bn + wn + nj * 16 + (lane & 15);
            #pragma unroll
            for (int q = 0; q < 4; ++q) {
                int r = row0 + q;
                if (r < M) C[(size_t)r * Nc + colc] = acc[mi][nj][q];
            }
        }

    // ---- fused alpha epilogue: per-wave 32-col partial dot, atomic combine --
    float av_s[2], av_d[2];
    #pragma unroll
    for (int nj = 0; nj < 2; ++nj) {
        int aidx = bn + wn + nj * 16 + fr;
        av_s[nj] = a_src[aidx];
        av_d[nj] = a_dst[aidx];
    }
    int head = bn / CPH;
    #pragma unroll
    for (int mi = 0; mi < 4; ++mi) {
        #pragma unroll
        for (int q = 0; q < 4; ++q) {
            float ps = acc[mi][0][q] * av_s[0] + acc[mi][1][q] * av_s[1];
            float pd = acc[mi][0][q] * av_d[0] + acc[mi][1][q] * av_d[1];
            #pragma unroll
            for (int o = 1; o < 16; o <<= 1) {
                ps += __shfl_xor(ps, o);
                pd += __shfl_xor(pd, o);
            }
            if (fr == 0) {
                int r = bm + wm + mi * 16 + (lane >> 4) * 4 + q;
                if (r < M) {
                    atomicAdd(&asT[(size_t)head * M + r], ps);
                    atomicAdd(&adT[(size_t)head * M + r], pd);
                }
            }
        }
    }
}

// ---------------- channel-sliced softmax-aggregate (R3-measured optimum) ----
// NSLICE=4 (R5: NSLICE=1 -> 86us HBM-latency; R7: NSLICE=8 -> 80us issue-
// bound; 4 -> ~63us). Fused softmax edge phase (pex variant: -1.5us kernel
// but +3 dispatches, R6/R7 net loss). GATHER4 / split s_off+s_p / VGPR 28 is
// the measured optimum (R8's int2+8-deep: VGPR 40, occ 71->55%, +8us).

template <int NSLICE, int SCH, int F, int HEADS, bool DO_ELU, bool SPLIT>
__global__ __launch_bounds__(256) void gat_aggregate_sliced(
        const float* __restrict__ h,      // [N, F]
        const float* __restrict__ asT,    // [HEADS][N]
        const float* __restrict__ adT,    // [HEADS][N]
        const int* __restrict__ row_ptr,
        const int* __restrict__ col,
        const float* __restrict__ bias,   // [F]
        float* __restrict__ out,          // [N, F]   (SPLIT=false)
        unsigned short* __restrict__ oh,  // [N, F]   (SPLIT=true)
        unsigned short* __restrict__ ol) {
    constexpr int CL = SCH / 4;           // lanes per edge (16 or 8)
    constexpr int E  = 64 / CL;           // parallel edges (4 or 8)
    constexpr int CPH = F / HEADS;        // channels per head
    __shared__ int   s_off[4][64];
    __shared__ float s_p[4][64];
    int slice = blockIdx.x & (NSLICE - 1);
    int ng = blockIdx.x >> 2;             // NSLICE == 4
    int wid = threadIdx.x >> 6, lane = threadIdx.x & 63;
    int v = ng * 4 + wid;
    if (v >= N_NODES) return;
    int head = (slice * SCH) / CPH;       // layers 1/2: slice == head; layer 3: 0
    int eg = lane / CL, cl = lane % CL;
    int r0 = row_ptr[v], r1 = row_ptr[v + 1];
    float ad = adT[head * N_NODES + v];
    const float* asrc = asT + head * N_NODES;
    float acc[4] = {};
    float lsum = 0.f;
    const char* hb = (const char*)(h + slice * SCH + cl * 4);

#define GATHER4(gg)                                                        \
    {                                                                      \
        int k0 = ((gg) + 0) * E + eg;                                      \
        int k1 = ((gg) + 1) * E + eg;                                      \
        int k2 = ((gg) + 2) * E + eg;                                      \
        int k3 = ((gg) + 3) * E + eg;                                      \
        float p0 = s_p[wid][k0]; int o0 = s_off[wid][k0];                  \
        float p1 = s_p[wid][k1]; int o1 = s_off[wid][k1];                  \
        float p2 = s_p[wid][k2]; int o2 = s_off[wid][k2];                  \
        float p3 = s_p[wid][k3]; int o3 = s_off[wid][k3];                  \
        float4 h0 = *(const float4*)(hb + o0);                             \
        float4 h1 = *(const float4*)(hb + o1);                             \
        float4 h2 = *(const float4*)(hb + o2);                             \
        float4 h3 = *(const float4*)(hb + o3);                             \
        acc[0] = fmaf(p0, h0.x, acc[0]);                                   \
        acc[1] = fmaf(p0, h0.y, acc[1]);                                   \
        acc[2] = fmaf(p0, h0.z, acc[2]);                                   \
        acc[3] = fmaf(p0, h0.w, acc[3]);                                   \
        acc[0] = fmaf(p1, h1.x, acc[0]);                                   \
        acc[1] = fmaf(p1, h1.y, acc[1]);                                   \
        acc[2] = fmaf(p1, h1.z, acc[2]);                                   \
        acc[3] = fmaf(p1, h1.w, acc[3]);                                   \
        acc[0] = fmaf(p2, h2.x, acc[0]);                                   \
        acc[1] = fmaf(p2, h2.y, acc[1]);                                   \
        acc[2] = fmaf(p2, h2.z, acc[2]);                                   \
        acc[3] = fmaf(p2, h2.w, acc[3]);                                   \
        acc[0] = fmaf(p3, h3.x, acc[0]);                                   \
        acc[1] = fmaf(p3, h3.y, acc[1]);                                   \
        acc[2] = fmaf(p3, h3.z, acc[2]);                                   \
        acc[3] = fmaf(p3, h3.w, acc[3]);                                   \
    }

    for (int base = r0; base < r1; base += 64) {
        int j = base + lane;
        bool valid = j < r1;
        int s = col[valid ? j : r0];
        float e = asrc[s] + ad;
        e = (e > 0.f) ? e : NEG_SLOPE * e;
        float p = valid ? __expf(e) : 0.f;
        lsum += p;
        s_p[wid][lane] = p;
        s_off[wid][lane] = s * (F * 4);   // byte offset of row s

        int nk = min(64, r1 - base);
        int nkg = (nk + E - 1) / E;       // <= 64/E
        int g = 0;
        for (; g + 4 <= nkg; g += 4) GATHER4(g);
        if (g < nkg) GATHER4(g);          // ragged tail: extra groups have p==0
    }
#undef GATHER4

    // full-wave softmax denominator
    #pragma unroll
    for (int o = 32; o; o >>= 1) lsum += __shfl_xor(lsum, o);
    // reduce acc across edge groups (lanes differing in bits >= log2(CL))
    #pragma unroll
    for (int c = 0; c < 4; ++c) {
        #pragma unroll
        for (int o = CL; o < 64; o <<= 1) acc[c] += __shfl_xor(acc[c], o);
    }
    if (eg == 0) {
        float inv = 1.f / (lsum + 1e-16f);
        int ch0 = slice * SCH + cl * 4;
        float o4[4];
        #pragma unroll
        for (int c = 0; c < 4; ++c) {
            float o = acc[c] * inv + bias[ch0 + c];
            if (DO_ELU) o = (o > 0.f) ? o : expm1f(o);
            o4[c] = o;
        }
        if constexpr (SPLIT) {
            ushort4 hv4, lv4;
            hv4.x = bf_hi(o4[0]); lv4.x = bf_hi(o4[0] - bf_f(hv4.x));
            hv4.y = bf_hi(o4[1]); lv4.y = bf_hi(o4[1] - bf_f(hv4.y));
            hv4.z = bf_hi(o4[2]); lv4.z = bf_hi(o4[2] - bf_f(hv4.z));
            hv4.w = bf_hi(o4[3]); lv4.w = bf_hi(o4[3] - bf_f(hv4.w));
            *(ushort4*)&oh[(size_t)v * F + ch0] = hv4;
            *(ushort4*)&ol[(size_t)v * F + ch0] = lv4;
        } else {
            *(float4*)&out[(size_t)v * F + ch0] =
                make_float4(o4[0], o4[1], o4[2], o4[3]);
        }
    }
}

// ---------------- global mean pool: 4-way row-split + atomic combine --------

__global__ void pool_mean4(const float* __restrict__ hout, const int* __restrict__ gstart,
                           float* __restrict__ gout) {
    int g = blockIdx.x;       // 64
    int q = blockIdx.y;       // 4 row-quarters
    int c = threadIdx.x;      // 128 channels
    int off = gstart[g], end = gstart[g + 1];
    float inv = 1.f / fmaxf((float)(end - off), 1.0f);
    float s = 0.f;
    for (int i = off + q; i < end; i += 4) s += hout[(size_t)i * 128 + c];
    atomicAdd(&gout[g * 128 + c], s * inv);
}

// ---------------- launch ----------------

static inline size_t align_up(size_t x, size_t a) { return (x + a - 1) & ~(a - 1); }

extern "C" void kernel_launch(void* const* d_in, const int* in_sizes, int n_in,
                              void* d_out, int out_size, void* d_ws, size_t ws_size,
                              hipStream_t stream) {
    const float* x   = (const float*)d_in[0];
    const int*   ei  = (const int*)d_in[1];
    const int*   bat = (const int*)d_in[2];
    const float* W1  = (const float*)d_in[3];
    const float* as1 = (const float*)d_in[4];
    const float* ad1 = (const float*)d_in[5];
    const float* b1  = (const float*)d_in[6];
    const float* W2  = (const float*)d_in[7];
    const float* as2 = (const float*)d_in[8];
    const float* ad2 = (const float*)d_in[9];
    const float* b2  = (const float*)d_in[10];
    const float* W3  = (const float*)d_in[11];
    const float* as3 = (const float*)d_in[12];
    const float* ad3 = (const float*)d_in[13];
    const float* b3  = (const float*)d_in[14];

    float* gout = (float*)d_out;                     // [G,128]
    float* hout = (float*)d_out + G_GRAPHS * 128;    // [N,128]

    char* w = (char*)d_ws;
    size_t o = 0;
    float* bufA = (float*)(w + o);           o = align_up(o + (size_t)N_NODES * 256 * 4, 256);
    unsigned short* Bh = (unsigned short*)(w + o); o = align_up(o + (size_t)N_NODES * 256 * 2, 256);
    unsigned short* Bl = (unsigned short*)(w + o); o = align_up(o + (size_t)N_NODES * 256 * 2, 256);
    unsigned short* xh = (unsigned short*)(w + o); o = align_up(o + (size_t)N_NODES * 128 * 2, 256);
    unsigned short* xl = (unsigned short*)(w + o); o = align_up(o + (size_t)N_NODES * 128 * 2, 256);
    unsigned short* Wt1h = (unsigned short*)(w + o); o = align_up(o + (size_t)256 * 128 * 2, 256);
    unsigned short* Wt1l = (unsigned short*)(w + o); o = align_up(o + (size_t)256 * 128 * 2, 256);
    unsigned short* Wt2h = (unsigned short*)(w + o); o = align_up(o + (size_t)256 * 256 * 2, 256);
    unsigned short* Wt2l = (unsigned short*)(w + o); o = align_up(o + (size_t)256 * 256 * 2, 256);
    unsigned short* Wt3h = (unsigned short*)(w + o); o = align_up(o + (size_t)128 * 256 * 2, 256);
    unsigned short* Wt3l = (unsigned short*)(w + o); o = align_up(o + (size_t)128 * 256 * 2, 256);
    // per-layer alpha buffers, CONTIGUOUS (zeroed as one 360000-f32 block)
    float* alpha = (float*)(w + o);
    float* asv1 = alpha;                  // [4][N]
    float* adv1 = alpha + 4 * N_NODES;    // [4][N]
    float* asv2 = alpha + 8 * N_NODES;    // [4][N]
    float* adv2 = alpha + 12 * N_NODES;   // [4][N]
    float* asv3 = alpha + 16 * N_NODES;   // [N]
    float* adv3 = alpha + 17 * N_NODES;   // [N]
    o = align_up(o + (size_t)18 * N_NODES * 4, 256);
    int* row_ptr = (int*)(w + o);  o = align_up(o + (size_t)(N_NODES + 1) * 4, 256);
    int* col     = (int*)(w + o);  o = align_up(o + (size_t)ET_EDGES * 4, 256);
    int* cnt     = (int*)(w + o);  o += (size_t)N_NODES * 4;        // cnt+cur contiguous
    int* cur     = (int*)(w + o);  o = align_up(o + (size_t)N_NODES * 4, 256);
    int* gstart  = (int*)(w + o);  o = align_up(o + (size_t)(G_GRAPHS + 1) * 4, 256);

    // ---- fused prep (splits + zeroing) + CSR build ----
    {
        int total = 640000 + 32768 + 65536 + 32768 + 10000 + 2048 + 90000;
        prep_split<<<(total + 255) / 256, 256, 0, stream>>>(
            x, W1, W2, W3, xh, xl, Wt1h, Wt1l, Wt2h, Wt2l, Wt3h, Wt3l, cnt, gout, alpha);
    }
    hist_dst<<<(ET_EDGES + 255) / 256, 256, 0, stream>>>(ei, cnt, bat, gstart);
    scan_rowptr<<<1, 1024, 0, stream>>>(cnt, row_ptr);
    fill_csr<<<(ET_EDGES + 255) / 256, 256, 0, stream>>>(ei, row_ptr, cur, col);

    int gm = (N_NODES + 127) / 128;   // 157
    int nb = (N_NODES + 3) / 4;       // 4 nodes per block
    int nbs = nb * 4;                 // x4 channel slices

    // ---- layer 1: 128 -> 4x64 (alpha fused into GEMM epilogue) ----
    gemm_split<64><<<dim3(gm, 4), 256, 0, stream>>>(
        xh, xl, Wt1h, Wt1l, bufA, N_NODES, 256, 128, as1, ad1, asv1, adv1);
    gat_aggregate_sliced<4, 64, 256, 4, true, true><<<nbs, 256, 0, stream>>>(
        bufA, asv1, adv1, row_ptr, col, b1, nullptr, Bh, Bl);

    // ---- layer 2: 256 -> 4x64 ----
    gemm_split<64><<<dim3(gm, 4), 256, 0, stream>>>(
        Bh, Bl, Wt2h, Wt2l, bufA, N_NODES, 256, 256, as2, ad2, asv2, adv2);
    gat_aggregate_sliced<4, 64, 256, 4, true, true><<<nbs, 256, 0, stream>>>(
        bufA, asv2, adv2, row_ptr, col, b2, nullptr, Bh, Bl);

    // ---- layer 3: 256 -> 128 (1 head) ----
    gemm_split<128><<<dim3(gm, 2), 256, 0, stream>>>(
        Bh, Bl, Wt3h, Wt3l, bufA, N_NODES, 128, 256, as3, ad3, asv3, adv3);
    gat_aggregate_sliced<4, 32, 128, 1, false, false><<<nbs, 256, 0, stream>>>(
        bufA, asv3, adv3, row_ptr, col, b3, hout, nullptr, nullptr);

    // ---- global mean pool ----
    pool_mean4<<<dim3(G_GRAPHS, 4), 128, 0, stream>>>(hout, gstart, gout);
}